// Round 8
// baseline (170.920 us; speedup 1.0000x reference)
//
#include <hip/hip_runtime.h>
#include <stdint.h>

#define BS 8
#define HH 192
#define WW 192
#define HW (HH*WW)     /* 36864 */
#define KK 16
#define QCAP 1024      /* u16 entries per wave queue */
#define DRAIN_HI 768u  /* a site adds <=256 -> never overflows QCAP */
#define PAD 1e-4f      /* covers approx(fma) vs exact(rn) sim error (~2e-6) */

typedef unsigned long long u64;

// ---------- helpers ----------

__device__ __forceinline__ uint32_t fkey(float f) {
    uint32_t u = __float_as_uint(f);
    uint32_t mask = (uint32_t)((int32_t)u >> 31) | 0x80000000u;
    return u ^ mask;
}
__device__ __forceinline__ float inv_fkey(uint32_t v) {
    uint32_t u = (v & 0x80000000u) ? (v ^ 0x80000000u) : ~v;
    return __uint_as_float(u);
}

__device__ __forceinline__ u64 umin64(u64 a, u64 b) { return a < b ? a : b; }

__device__ __forceinline__ u64 wave_min_u64(u64 v) {
    #pragma unroll
    for (int off = 32; off >= 1; off >>= 1) {
        uint32_t lo = (uint32_t)v, hi = (uint32_t)(v >> 32);
        lo = __shfl_xor(lo, off, 64);
        hi = __shfl_xor(hi, off, 64);
        u64 o = ((u64)hi << 32) | lo;
        v = umin64(v, o);
    }
    return v;
}

__device__ __forceinline__ float wave_min_f32(float v) {
    #pragma unroll
    for (int off = 32; off >= 1; off >>= 1)
        v = fminf(v, __shfl_xor(v, off, 64));
    return v;
}

__device__ __forceinline__ void insert64(u64 (&kept)[KK], u64 key) {
    #pragma unroll
    for (int j = KK - 1; j >= 1; --j) {
        u64 a = kept[j - 1];
        u64 mn = umin64(kept[j], key);
        kept[j] = (key < a) ? a : mn;
    }
    kept[0] = umin64(kept[0], key);
}

__device__ __forceinline__ uint32_t lanerank(u64 pm) {
    return __builtin_amdgcn_mbcnt_hi((uint32_t)(pm >> 32),
             __builtin_amdgcn_mbcnt_lo((uint32_t)pm, 0));
}

// binary search: smallest hi' in [lo,hi] with wave-count(khi <= hi') >= 16.
// Sound when count(hi) >= 16 and lo <= answer.
__device__ __forceinline__ uint32_t refine_u32(const uint32_t (&khi)[KK],
                                               uint32_t lo, uint32_t hi, int iters) {
    #pragma unroll 1
    for (int t = 0; t < iters; ++t) {
        uint32_t mid = lo + ((hi - lo) >> 1);
        int c = 0;
        #pragma unroll
        for (int j = 0; j < KK; ++j) c += (khi[j] <= mid) ? 1 : 0;
        #pragma unroll
        for (int off = 32; off >= 1; off >>= 1) c += __shfl_xor(c, off, 64);
        if (c >= KK) hi = mid; else lo = mid + 1;
    }
    return hi;
}

__device__ __forceinline__ uint32_t refine_k(const u64 (&kept)[KK], uint32_t hi, int iters) {
    uint32_t kh[KK];
    #pragma unroll
    for (int j = 0; j < KK; ++j) kh[j] = (uint32_t)(kept[j] >> 32);
    return refine_u32(kh, 0x00800000u, hi, iters);
}

__device__ __forceinline__ float exact_rsq(float a, float b, float c) {
    return __fadd_rn(__fadd_rn(__fmul_rn(a, a), __fmul_rn(b, b)), __fmul_rn(c, c));
}
__device__ __forceinline__ float exact_sim(float c0, float c1, float c2, float rsq, float4 pq) {
    float cr = __fadd_rn(__fadd_rn(__fmul_rn(c0, pq.x), __fmul_rn(c1, pq.y)), __fmul_rn(c2, pq.z));
    return __fadd_rn(__fsub_rn(rsq, __fmul_rn(2.0f, cr)), pq.w);
}

__device__ __forceinline__ int stage_compact(const u64 (&kept)[KK], uint32_t tk, u64* cb, int lane) {
    int c = 0;
    #pragma unroll
    for (int j = 0; j < KK; ++j) c += ((uint32_t)(kept[j] >> 32) <= tk) ? 1 : 0;
    int pref = c;
    #pragma unroll
    for (int i = 1; i < 64; i <<= 1) {
        int t = __shfl_up(pref, i, 64);
        if (lane >= i) pref += t;
    }
    int M = __shfl(pref, 63, 64);
    int base = pref - c;
    if (M <= 64) {
        #pragma unroll
        for (int j = 0; j < KK; ++j)
            if (j < c) cb[base + j] = kept[j];     // kept sorted: prefix = entries <= tk
    }
    return M;
}

__device__ __forceinline__ void select16(u64 (&kept)[KK], int M, const u64* cb, u64* mrow, int lane) {
    if (M <= 64) {
        u64 my = (lane < M) ? cb[lane] : ~0ull;
        int rank = 0;
        #pragma unroll 1
        for (int m = 0; m < M; ++m) rank += (cb[m] < my) ? 1 : 0;
        if (lane < M && rank < KK) mrow[rank] = my;
    } else {   // exact fallback (rare)
        #pragma unroll 1
        for (int r = 0; r < KK; ++r) {
            u64 m = wave_min_u64(kept[0]);
            if (kept[0] == m) {
                #pragma unroll
                for (int j = 0; j < KK - 1; ++j) kept[j] = kept[j + 1];
                kept[KK - 1] = ~0ull;
            }
            if (lane == 0) mrow[r] = m;
        }
    }
}

// ---------- single fused kernel: block = query (b,l); 4 waves split image ----------
__global__ __launch_bounds__(256) void topk_kernel(const float* __restrict__ pred,
                                                   const float* __restrict__ ref,
                                                   double* __restrict__ dacc,
                                                   uint32_t* __restrict__ dcnt,
                                                   float* __restrict__ out) {
    __shared__ unsigned short qbuf[4][QCAP];   // 8 KB
    __shared__ u64 cbufs[4][64];               // 2 KB
    __shared__ u64 mbuf[64];                   // 0.5 KB
    __shared__ float4 spool;

    int lane = threadIdx.x & 63;
    int wid  = threadIdx.x >> 6;
    int b = blockIdx.x & 7;            // XCD swizzle: image -> one XCD's L2
    int l = blockIdx.x >> 3;           // 0..255

    if (l == 255) {                    // its top-16 feeds only excluded row 0
        if (threadIdx.x == 0) {
            __threadfence();
            uint32_t old = atomicAdd(dcnt, 1u);
            if (old == 2047u) {
                double s = atomicAdd(dacc, 0.0);
                out[0] = (float)(s / 2040.0);
            }
        }
        return;
    }

    // ---- pooled for this query ----
    if (threadIdx.x == 0) {
        int i = l * BS + b;            // scrambled flat grid row
        int b2 = i >> 8, l2 = i & 255;
        const float* pr = pred + ((b2 * 256 + l2) * 8);
        float x = pr[0], y = pr[1];
        float fx = rintf(__fsub_rn(__fmul_rn(x, 192.0f), 0.5f));
        float fy = rintf(__fsub_rn(__fmul_rn(y, 192.0f), 0.5f));
        int ix = (int)fx, iy = (int)fy;
        int inb = (ix >= 0 && ix < WW && iy >= 0 && iy < HH) ? 1 : 0;
        int ixc = min(max(ix, 0), WW - 1);
        int iyc = min(max(iy, 0), HH - 1);
        float m = (float)inb;
        const float* img = ref + b * 3 * HW + iyc * WW + ixc;
        float p0 = __fmul_rn(img[0], m);
        float p1 = __fmul_rn(img[HW], m);
        float p2 = __fmul_rn(img[2 * HW], m);
        float psq = __fadd_rn(__fadd_rn(__fmul_rn(p0, p0), __fmul_rn(p1, p1)), __fmul_rn(p2, p2));
        spool = make_float4(p0, p1, p2, psq);
    }
    __syncthreads();
    float4 pq = spool;

    const float*  imgb = ref + (size_t)b * 3 * HW;
    const float4* p0g  = (const float4*)imgb;
    int wq4 = wid * 2304;              // wave's quarter (float4 units)
    unsigned short* qw = qbuf[wid];

    // ---- warm-up: sites 0..3, approx (fma) sims ----
    float ws[KK];
    #pragma unroll
    for (int it = 0; it < 4; ++it) {
        int v = wq4 + it * 64 + lane;
        float4 a0 = p0g[v], a1 = p0g[v + 9216], a2 = p0g[v + 18432];
        #define WARM(comp, e)                                                              \
        {                                                                                  \
            float rsf = fmaf(a2.comp, a2.comp, fmaf(a1.comp, a1.comp, a0.comp*a0.comp));   \
            float crf = fmaf(a2.comp, pq.z, fmaf(a1.comp, pq.y, a0.comp*pq.x));            \
            ws[it * 4 + e] = fmaf(-2.0f, crf, rsf) + pq.w;                                 \
        }
        WARM(x, 0) WARM(y, 1) WARM(z, 2) WARM(w, 3)
        #undef WARM
    }

    // ---- tau from warm sample: binary search seeded by data spread ----
    uint32_t tk;
    {
        float lmn = ws[0], lmx = ws[0];
        #pragma unroll
        for (int j = 1; j < KK; ++j) { lmn = fminf(lmn, ws[j]); lmx = fmaxf(lmx, ws[j]); }
        float gmn = wave_min_f32(lmn);
        float gmx = wave_min_f32(lmx);     // min over lanes of per-lane max: count(<=) >= 16
        uint32_t kh[KK];
        #pragma unroll
        for (int j = 0; j < KK; ++j) kh[j] = fkey(ws[j]);
        tk = refine_u32(kh, fkey(gmn), fkey(gmx), 16);
    }
    float tauf = inv_fkey(tk) + 2.0f * PAD;   // pass bound: candidate approx <= tauf
    uint32_t brk = fkey(tauf);                // sound bracket for first exact refine
    float h = (pq.w - tauf) * 0.5f;           // filter: pass <=> cr >= rsf*0.5 + h

    u64 kept[KK];
    #pragma unroll
    for (int j = 0; j < KK; ++j) kept[j] = ~0ull;
    uint32_t scnt = 0;
    bool first = true;

    #define PUSH_SITE(nib, v)                                                   \
    {                                                                           \
        uint32_t cnt = __popc(nib);                                             \
        u64 B0 = __ballot((cnt & 1u) != 0);                                     \
        u64 B1 = __ballot((cnt & 2u) != 0);                                     \
        u64 B2 = __ballot((cnt & 4u) != 0);                                     \
        uint32_t off = scnt + lanerank(B0) + 2u*lanerank(B1) + 4u*lanerank(B2); \
        uint32_t p = (uint32_t)(v) << 2;                                        \
        if ((nib) & 1u) { qw[off++] = (unsigned short)p; }                      \
        if ((nib) & 2u) { qw[off++] = (unsigned short)(p + 1); }                \
        if ((nib) & 4u) { qw[off++] = (unsigned short)(p + 2); }                \
        if ((nib) & 8u) { qw[off++] = (unsigned short)(p + 3); }                \
        scnt += (uint32_t)__popcll(B0) + 2u*(uint32_t)__popcll(B1)              \
              + 4u*(uint32_t)__popcll(B2);                                      \
    }

    #define DRAIN(ITERS)                                                        \
    {                                                                           \
        for (uint32_t e = (uint32_t)lane; e < scnt; e += 64) {                  \
            uint32_t p = (uint32_t)qw[e];                                       \
            float c0 = imgb[p], c1 = imgb[p + HW], c2 = imgb[p + 2 * HW];       \
            float rs = exact_rsq(c0, c1, c2);                                   \
            float s  = exact_sim(c0, c1, c2, rs, pq);                           \
            insert64(kept, ((u64)fkey(s) << 32) | p);                           \
        }                                                                       \
        scnt = 0;                                                               \
        tk = refine_k(kept, first ? brk : tk, (ITERS));                         \
        first = false;                                                          \
        tauf = inv_fkey(tk) + PAD;                                              \
        h = (pq.w - tauf) * 0.5f;                                               \
    }

    // ---- warm survivors -> queue (>=16 guaranteed pushes) ----
    #pragma unroll
    for (int it = 0; it < 4; ++it) {
        uint32_t nib = (ws[it*4+0] <= tauf ? 1u : 0u) | (ws[it*4+1] <= tauf ? 2u : 0u)
                     | (ws[it*4+2] <= tauf ? 4u : 0u) | (ws[it*4+3] <= tauf ? 8u : 0u);
        uint32_t v = (uint32_t)(wq4 + it * 64 + lane);
        PUSH_SITE(nib, v)
    }
    if (scnt >= DRAIN_HI) DRAIN(12)

    // ---- main scan: sites 4..35, 1-site prefetch, FMA filter ----
    int vp = wq4 + 4 * 64 + lane;
    float4 n0 = p0g[vp], n1 = p0g[vp + 9216], n2 = p0g[vp + 18432];

    #pragma unroll 1
    for (int it = 4; it < 36; ++it) {
        float4 a0 = n0, a1 = n1, a2 = n2;
        int itn = (it < 35) ? it + 1 : 35;
        int vn = wq4 + itn * 64 + lane;
        n0 = p0g[vn]; n1 = p0g[vn + 9216]; n2 = p0g[vn + 18432];

        uint32_t nib = 0;
        #define FILT(comp, bitv)                                                           \
        {                                                                                  \
            float rsf = fmaf(a2.comp, a2.comp, fmaf(a1.comp, a1.comp, a0.comp*a0.comp));   \
            float crf = fmaf(a2.comp, pq.z, fmaf(a1.comp, pq.y, a0.comp*pq.x));            \
            if (crf >= fmaf(rsf, 0.5f, h)) nib |= bitv;                                    \
        }
        FILT(x, 1u) FILT(y, 2u) FILT(z, 4u) FILT(w, 8u)
        #undef FILT

        if (__ballot(nib != 0)) {
            uint32_t v = (uint32_t)(wq4 + it * 64 + lane);
            PUSH_SITE(nib, v)
            if (scnt >= DRAIN_HI) DRAIN(12)
        }
    }
    // final drain + refine for compact cut
    DRAIN(18)
    #undef DRAIN
    #undef PUSH_SITE

    // ---- per-wave top-16 -> mbuf ----
    int M = stage_compact(kept, tk, cbufs[wid], lane);
    select16(kept, M, cbufs[wid], &mbuf[wid * KK], lane);
    __syncthreads();

    // ---- wave 0: merge 64 candidates, argmin vs row l+1, accumulate ----
    if (wid == 0) {
        u64 v = mbuf[lane];            // 64 distinct keys (disjoint quarters)
        int rank = 0;
        #pragma unroll 1
        for (int m = 0; m < 64; ++m) {
            uint32_t lo = __shfl((uint32_t)v, m, 64);
            uint32_t hi = __shfl((uint32_t)(v >> 32), m, 64);
            u64 o = ((u64)hi << 32) | lo;
            rank += (o < v) ? 1 : 0;
        }
        int row = l + 1;               // 1..255
        float px1 = pred[(size_t)(b * 256 + row) * 8 + 0];
        float py1 = pred[(size_t)(b * 256 + row) * 8 + 1];
        float tx = 0.0f, ty = 0.0f;
        u64 dkey = ~0ull;
        if (rank < KK) {
            uint32_t idx = (uint32_t)v;
            tx = (float)(idx % WW) / 192.0f;
            ty = (float)(idx / WW) / 192.0f;
            float dx = __fsub_rn(px1, tx);
            float dy = __fsub_rn(py1, ty);
            float d = __fadd_rn(__fmul_rn(dx, dx), __fmul_rn(dy, dy));
            dkey = ((u64)__float_as_uint(d) << 32) | (uint32_t)rank;  // argmin tie -> low rank
        }
        u64 wmin = wave_min_u64(dkey);
        float term = 0.0f;
        if (dkey == wmin && rank < KK) {
            float ex = __fsub_rn(px1, tx);
            float ey = __fsub_rn(py1, ty);
            term = __fadd_rn(__fmul_rn(ex, ex), __fmul_rn(ey, ey));
        }
        // one lane holds the term; wave-sum (63 zeros) keeps it exact
        #pragma unroll
        for (int off = 32; off >= 1; off >>= 1)
            term += __shfl_xor(term, off, 64);
        if (lane == 0) {
            atomicAdd(dacc, (double)term);
            __threadfence();
            uint32_t old = atomicAdd(dcnt, 1u);
            if (old == 2047u) {
                double s = atomicAdd(dacc, 0.0);
                out[0] = (float)(s / 2040.0);
            }
        }
    }
}

// ---------- launch ----------
extern "C" void kernel_launch(void* const* d_in, const int* in_sizes, int n_in,
                              void* d_out, int out_size, void* d_ws, size_t ws_size,
                              hipStream_t stream) {
    const float* pred = (const float*)d_in[0];   // (8,256,8) f32
    const float* ref  = (const float*)d_in[1];   // (8,3,192,192) f32
    float* out = (float*)d_out;

    double*   dacc = (double*)d_ws;              // 8 B accumulator
    uint32_t* dcnt = (uint32_t*)((char*)d_ws + 8);

    hipMemsetAsync(d_ws, 0, 16, stream);
    topk_kernel<<<2048, 256, 0, stream>>>(pred, ref, dacc, dcnt, out);
}

// Round 9
// 157.640 us; speedup vs baseline: 1.0842x; 1.0842x over previous
//
#include <hip/hip_runtime.h>
#include <stdint.h>

#define BS 8
#define HH 192
#define WW 192
#define HW (HH*WW)     /* 36864 */
#define KK 16
#define KCAP 256       /* u64 survivor keys per wave (expected ~92, +17 sigma) */
#define PAD 1e-4f      /* covers approx(fma) vs exact(rn) sim error (~2e-6) */

typedef unsigned long long u64;

// ---------- helpers ----------

__device__ __forceinline__ uint32_t fkey(float f) {
    uint32_t u = __float_as_uint(f);
    uint32_t mask = (uint32_t)((int32_t)u >> 31) | 0x80000000u;
    return u ^ mask;
}
__device__ __forceinline__ float inv_fkey(uint32_t v) {
    uint32_t u = (v & 0x80000000u) ? (v ^ 0x80000000u) : ~v;
    return __uint_as_float(u);
}

__device__ __forceinline__ u64 umin64(u64 a, u64 b) { return a < b ? a : b; }

__device__ __forceinline__ u64 wave_min_u64(u64 v) {
    #pragma unroll
    for (int off = 32; off >= 1; off >>= 1) {
        uint32_t lo = (uint32_t)v, hi = (uint32_t)(v >> 32);
        lo = __shfl_xor(lo, off, 64);
        hi = __shfl_xor(hi, off, 64);
        u64 o = ((u64)hi << 32) | lo;
        v = umin64(v, o);
    }
    return v;
}

__device__ __forceinline__ float wave_min_f32(float v) {
    #pragma unroll
    for (int off = 32; off >= 1; off >>= 1)
        v = fminf(v, __shfl_xor(v, off, 64));
    return v;
}

__device__ __forceinline__ float exact_rsq(float a, float b, float c) {
    return __fadd_rn(__fadd_rn(__fmul_rn(a, a), __fmul_rn(b, b)), __fmul_rn(c, c));
}
__device__ __forceinline__ float exact_sim(float c0, float c1, float c2, float rsq, float4 pq) {
    float cr = __fadd_rn(__fadd_rn(__fmul_rn(c0, pq.x), __fmul_rn(c1, pq.y)), __fmul_rn(c2, pq.z));
    return __fadd_rn(__fsub_rn(rsq, __fmul_rn(2.0f, cr)), pq.w);
}

// ---------- single fused kernel: block = query (b,l); 4 waves split image ----------
__global__ __launch_bounds__(256) void topk_kernel(const float* __restrict__ pred,
                                                   const float* __restrict__ ref,
                                                   double* __restrict__ dacc,
                                                   uint32_t* __restrict__ dcnt,
                                                   float* __restrict__ out) {
    __shared__ u64 kbuf[4][KCAP];      // 8 KB survivor keys
    __shared__ u64 mbuf[64];           // 4 waves x 16 sorted candidates
    __shared__ uint32_t wtk[4];
    __shared__ float4 spool;

    const int lane = threadIdx.x & 63;
    const int wid  = threadIdx.x >> 6;
    const int b = blockIdx.x & 7;      // XCD swizzle: image -> one XCD's L2
    const int l = blockIdx.x >> 3;     // 0..255

    if (l == 255) {                    // its top-16 feeds only excluded row 0
        if (threadIdx.x == 0) {
            __threadfence();
            uint32_t old = atomicAdd(dcnt, 1u);
            if (old == 2047u) {
                double s = atomicAdd(dacc, 0.0);
                out[0] = (float)(s / 2040.0);
            }
        }
        return;
    }

    // ---- pooled for this query ----
    if (threadIdx.x == 0) {
        int i = l * BS + b;            // scrambled flat grid row
        int b2 = i >> 8, l2 = i & 255;
        const float* pr = pred + ((b2 * 256 + l2) * 8);
        float x = pr[0], y = pr[1];
        float fx = rintf(__fsub_rn(__fmul_rn(x, 192.0f), 0.5f));
        float fy = rintf(__fsub_rn(__fmul_rn(y, 192.0f), 0.5f));
        int ix = (int)fx, iy = (int)fy;
        int inb = (ix >= 0 && ix < WW && iy >= 0 && iy < HH) ? 1 : 0;
        int ixc = min(max(ix, 0), WW - 1);
        int iyc = min(max(iy, 0), HH - 1);
        float m = (float)inb;
        const float* img = ref + b * 3 * HW + iyc * WW + ixc;
        float p0 = __fmul_rn(img[0], m);
        float p1 = __fmul_rn(img[HW], m);
        float p2 = __fmul_rn(img[2 * HW], m);
        float psq = __fadd_rn(__fadd_rn(__fmul_rn(p0, p0), __fmul_rn(p1, p1)), __fmul_rn(p2, p2));
        spool = make_float4(p0, p1, p2, psq);
    }
    __syncthreads();
    const float4 pq = spool;

    const float*  imgb = ref + (size_t)b * 3 * HW;
    const float4* p0g  = (const float4*)imgb;
    const int wq4 = wid * 2304;        // wave's quarter (float4 units)

    // ---- warm-up: sites 0..3, approx (fma) sims ----
    float ws[KK];
    #pragma unroll
    for (int it = 0; it < 4; ++it) {
        int v = wq4 + it * 64 + lane;
        float4 a0 = p0g[v], a1 = p0g[v + 9216], a2 = p0g[v + 18432];
        #define WARM(comp, e)                                                              \
        {                                                                                  \
            float rsf = fmaf(a2.comp, a2.comp, fmaf(a1.comp, a1.comp, a0.comp*a0.comp));   \
            float crf = fmaf(a2.comp, pq.z, fmaf(a1.comp, pq.y, a0.comp*pq.x));            \
            ws[it * 4 + e] = fmaf(-2.0f, crf, rsf) + pq.w;                                 \
        }
        WARM(x, 0) WARM(y, 1) WARM(z, 2) WARM(w, 3)
        #undef WARM
    }

    // ---- tau: 16th smallest of the 64 per-lane minima (ballot binary search) ----
    {
        float lmn = ws[0], lmx = ws[0];
        #pragma unroll
        for (int j = 1; j < KK; ++j) { lmn = fminf(lmn, ws[j]); lmx = fmaxf(lmx, ws[j]); }
        uint32_t kmin = fkey(lmn);
        uint32_t lo = fkey(wave_min_f32(lmn));        // <= answer
        uint32_t hi = fkey(wave_min_f32(lmx));        // count(<=hi) >= 16 (min-of-maxima lane)
        #pragma unroll 1
        for (int t = 0; t < 20; ++t) {
            uint32_t mid = lo + ((hi - lo) >> 1);
            int c = __popcll(__ballot(kmin <= mid));
            if (c >= KK) hi = mid; else lo = mid + 1;
        }
        wtk[wid] = hi;                                 // sound upper bound, count >= 16
    }
    __syncthreads();
    const uint32_t tk = min(min(wtk[0], wtk[1]), min(wtk[2], wtk[3]));  // still sound
    const float tauf = inv_fkey(tk) + 2.0f * PAD;     // padded pass threshold
    const float h = (pq.w - tauf) * 0.5f;             // filter: pass <=> crf >= rsf*0.5 + h

    // ---- mask words: bit (site_local*4+elem); word w covers sites w*8..w*8+7 ----
    uint32_t m0w = 0, m1w = 0, m2w = 0, m3w = 0, m4w = 0;
    #pragma unroll
    for (int j = 0; j < KK; ++j)
        m0w |= (ws[j] <= tauf ? 1u : 0u) << j;        // warm sites 0..3 -> bits 0..15

    // ---- main scan: sites 4..35, branch-free, 1-site prefetch ----
    #define LOADS(S, A0, A1, A2)                                    \
    { int vv = wq4 + (S) * 64 + lane;                               \
      A0 = p0g[vv]; A1 = p0g[vv + 9216]; A2 = p0g[vv + 18432]; }

    #define FILT(comp, bitv)                                                           \
    {                                                                                  \
        float rsf = fmaf(a2.comp, a2.comp, fmaf(a1.comp, a1.comp, a0.comp*a0.comp));   \
        float crf = fmaf(a2.comp, pq.z, fmaf(a1.comp, pq.y, a0.comp*pq.x));            \
        if (crf >= fmaf(rsf, 0.5f, h)) nib |= (bitv);                                  \
    }

    float4 n0, n1, n2;
    LOADS(4, n0, n1, n2)

    #define CHUNK(MW, S0, S1, SH0)                                  \
    {                                                               \
        uint32_t sh = (SH0);                                        \
        _Pragma("unroll 1")                                         \
        for (int it = (S0); it < (S1); ++it) {                      \
            float4 a0 = n0, a1 = n1, a2 = n2;                       \
            int nxt = (it + 1 < 36) ? it + 1 : 35;                  \
            LOADS(nxt, n0, n1, n2)                                  \
            uint32_t nib = 0;                                       \
            FILT(x, 1u) FILT(y, 2u) FILT(z, 4u) FILT(w, 8u)         \
            MW |= nib << sh;                                        \
            sh += 4;                                                \
        }                                                           \
    }
    CHUNK(m0w,  4,  8, 16)
    CHUNK(m1w,  8, 16, 0)
    CHUNK(m2w, 16, 24, 0)
    CHUNK(m3w, 24, 32, 0)
    CHUNK(m4w, 32, 36, 0)
    #undef CHUNK
    #undef FILT
    #undef LOADS

    // ---- one push/exact pass: prefix offsets, gather, exact keys -> LDS ----
    int cnt = __popc(m0w) + __popc(m1w) + __popc(m2w) + __popc(m3w) + __popc(m4w);
    int pref = cnt;
    #pragma unroll
    for (int i = 1; i < 64; i <<= 1) {
        int t = __shfl_up(pref, i, 64);
        if (lane >= i) pref += t;
    }
    int scnt = __shfl(pref, 63, 64);
    int off = pref - cnt;
    u64* kw = kbuf[wid];

    #define PROC(MW, WIDX)                                                  \
    {                                                                       \
        uint32_t w = (MW);                                                  \
        while (w) {                                                         \
            int i = __ffs(w) - 1; w &= w - 1;                               \
            int site = (WIDX) * 8 + (i >> 2);                               \
            uint32_t p = (uint32_t)((wq4 + site * 64 + lane) * 4 + (i & 3));\
            float c0 = imgb[p], c1 = imgb[p + HW], c2 = imgb[p + 2 * HW];   \
            float rs = exact_rsq(c0, c1, c2);                               \
            float s  = exact_sim(c0, c1, c2, rs, pq);                       \
            if (off < KCAP) kw[off] = ((u64)fkey(s) << 32) | p;             \
            off++;                                                          \
        }                                                                   \
    }
    PROC(m0w, 0) PROC(m1w, 1) PROC(m2w, 2) PROC(m3w, 3) PROC(m4w, 4)
    #undef PROC
    if (scnt > KCAP) scnt = KCAP;

    // ---- per-lane <=4 keys, sort-4, 16-round wave min-pop -> sorted top-16 ----
    u64 k0 = (lane       < scnt) ? kw[lane]       : ~0ull;
    u64 k1 = (lane + 64  < scnt) ? kw[lane + 64]  : ~0ull;
    u64 k2 = (lane + 128 < scnt) ? kw[lane + 128] : ~0ull;
    u64 k3 = (lane + 192 < scnt) ? kw[lane + 192] : ~0ull;
    #define CSWAP(A, B) { u64 mn = umin64(A, B); u64 mx = (A < B) ? B : A; A = mn; B = mx; }
    CSWAP(k0, k1) CSWAP(k2, k3) CSWAP(k0, k2) CSWAP(k1, k3) CSWAP(k1, k2)
    #undef CSWAP

    #pragma unroll 1
    for (int r = 0; r < KK; ++r) {
        u64 m = wave_min_u64(k0);
        if (lane == 0) mbuf[wid * KK + r] = m;
        if (k0 == m && m != ~0ull) {   // unique owner (keys distinct); sentinel pops nothing
            k0 = k1; k1 = k2; k2 = k3; k3 = ~0ull;
        }
    }
    __syncthreads();

    // ---- wave 0: merge 64 candidates, argmin vs row l+1, accumulate ----
    if (wid == 0) {
        u64 v = mbuf[lane];            // real keys distinct; ~0 sentinels rank last
        int rank = 0;
        #pragma unroll 1
        for (int m = 0; m < 64; ++m) {
            uint32_t lo = __shfl((uint32_t)v, m, 64);
            uint32_t hi = __shfl((uint32_t)(v >> 32), m, 64);
            u64 o = ((u64)hi << 32) | lo;
            rank += (o < v) ? 1 : 0;
        }
        bool valid = (v != ~0ull) && (rank < KK);   // block survivors >= 16 -> top-16 all real
        int row = l + 1;               // 1..255
        float px1 = pred[(size_t)(b * 256 + row) * 8 + 0];
        float py1 = pred[(size_t)(b * 256 + row) * 8 + 1];
        float tx = 0.0f, ty = 0.0f;
        u64 dkey = ~0ull;
        if (valid) {
            uint32_t idx = (uint32_t)v;
            tx = (float)(idx % WW) / 192.0f;
            ty = (float)(idx / WW) / 192.0f;
            float dx = __fsub_rn(px1, tx);
            float dy = __fsub_rn(py1, ty);
            float d = __fadd_rn(__fmul_rn(dx, dx), __fmul_rn(dy, dy));
            dkey = ((u64)__float_as_uint(d) << 32) | (uint32_t)rank;  // argmin tie -> low rank
        }
        u64 wmin = wave_min_u64(dkey);
        float term = 0.0f;
        if (dkey == wmin && valid) {
            float ex = __fsub_rn(px1, tx);
            float ey = __fsub_rn(py1, ty);
            term = __fadd_rn(__fmul_rn(ex, ex), __fmul_rn(ey, ey));
        }
        #pragma unroll
        for (int off2 = 32; off2 >= 1; off2 >>= 1)
            term += __shfl_xor(term, off2, 64);     // 63 zeros + term: exact
        if (lane == 0) {
            atomicAdd(dacc, (double)term);
            __threadfence();
            uint32_t old = atomicAdd(dcnt, 1u);
            if (old == 2047u) {
                double s = atomicAdd(dacc, 0.0);
                out[0] = (float)(s / 2040.0);
            }
        }
    }
}

// ---------- launch ----------
extern "C" void kernel_launch(void* const* d_in, const int* in_sizes, int n_in,
                              void* d_out, int out_size, void* d_ws, size_t ws_size,
                              hipStream_t stream) {
    const float* pred = (const float*)d_in[0];   // (8,256,8) f32
    const float* ref  = (const float*)d_in[1];   // (8,3,192,192) f32
    float* out = (float*)d_out;

    double*   dacc = (double*)d_ws;              // 8 B accumulator
    uint32_t* dcnt = (uint32_t*)((char*)d_ws + 8);

    hipMemsetAsync(d_ws, 0, 16, stream);
    topk_kernel<<<2048, 256, 0, stream>>>(pred, ref, dacc, dcnt, out);
}